// Round 1
// baseline (601.805 us; speedup 1.0000x reference)
//
#include <hip/hip_runtime.h>

// LIF forward recurrence, bit-exact vs the numpy reference.
//
// Reference per step (fp32, left-to-right evaluation):
//   th_eff = 1.0 + 1.5*a
//   v      = (v - v/20.0) + I_t
//   s      = (v >= th_eff) ? 1.0 : 0.0   // STE forward value is EXACTLY s_hard
//                                        // (Sterbenz: (1-y)+y == 1 for y in [0.5,1];
//                                        //  (0-y)+y == 0 always) -> sigmoid irrelevant
//   s_num += s
//   v      = s ? -0.5 : v                // v*(1-s) + V_RESET*s with s in {0,1} is exact
//   a      = (a - a/100.0) + s
//
// All ops use __f*_rn intrinsics: correctly rounded, never FMA-contracted,
// matching numpy fp32 semantics bit-for-bit (division is IEEE-correct via
// __fdiv_rn; hipcc default is correctly-rounded fp32 divide anyway).

#define LIF_L 2048

__device__ __forceinline__ float lif_step(float It, float& v, float& a, float& snum) {
    // th_eff from OLD a (before a update)
    float th = __fadd_rn(1.0f, __fmul_rn(1.5f, a));
    // v = (v - v/20) + I_t, exact op order
    float vn = __fadd_rn(__fsub_rn(v, __fdiv_rn(v, 20.0f)), It);
    bool fire = (vn >= th);
    float s = fire ? 1.0f : 0.0f;
    snum = __fadd_rn(snum, s);
    v = fire ? -0.5f : vn;
    // a = (a - a/100) + s, exact op order (old a)
    a = __fadd_rn(__fsub_rn(a, __fdiv_rn(a, 100.0f)), s);
    return s;
}

__global__ __launch_bounds__(64) void lif_fwd(const float* __restrict__ I,
                                              float* __restrict__ spikes,
                                              float* __restrict__ series) {
    const int row = blockIdx.x * 64 + threadIdx.x;
    const size_t base = (size_t)row * (size_t)LIF_L;

    const float4* __restrict__ I4  = reinterpret_cast<const float4*>(I + base);
    float4* __restrict__ sp4       = reinterpret_cast<float4*>(spikes + base);
    float4* __restrict__ se4       = reinterpret_cast<float4*>(series + base);

    float v = 0.0f, a = 0.0f, snum = 0.0f;

    constexpr int NCH = LIF_L / 4;  // 512 float4 chunks

    // Software pipeline: keep ~2 chunks of input in flight to cover HBM
    // latency at 1 wave/CU occupancy.
    float4 cur = I4[0];
    float4 nxt = I4[1];

    for (int c = 0; c < NCH; ++c) {
        float4 in = cur;
        cur = nxt;
        if (c + 2 < NCH) nxt = I4[c + 2];

        float4 os, on;
        os.x = lif_step(in.x, v, a, snum); on.x = snum;
        os.y = lif_step(in.y, v, a, snum); on.y = snum;
        os.z = lif_step(in.z, v, a, snum); on.z = snum;
        os.w = lif_step(in.w, v, a, snum); on.w = snum;

        sp4[c] = os;
        se4[c] = on;
    }
}

extern "C" void kernel_launch(void* const* d_in, const int* in_sizes, int n_in,
                              void* d_out, int out_size, void* d_ws, size_t ws_size,
                              hipStream_t stream) {
    const float* I = (const float*)d_in[0];
    const int B = in_sizes[0] / LIF_L;          // 16384
    float* spikes = (float*)d_out;              // (B, L) flat
    float* series = (float*)d_out + (size_t)B * LIF_L;  // (B, L) flat

    const int threads = 64;
    const int blocks = B / threads;             // 256 blocks -> 1 wave/CU
    lif_fwd<<<blocks, threads, 0, stream>>>(I, spikes, series);
}

// Round 2
// 479.158 us; speedup vs baseline: 1.2560x; 1.2560x over previous
//
#include <hip/hip_runtime.h>

// LIF forward recurrence, bit-exact vs the numpy fp32 reference.
//
// Per step (exact op order, correctly-rounded, no FMA contraction):
//   th   = 1 + 1.5*a
//   v    = (v - v/20) + I_t
//   s    = (v >= th) ? 1 : 0        // STE forward == s_hard exactly (Sterbenz)
//   snum += s
//   v    = s ? -0.5 : v             // exact for s in {0,1}
//   a    = (a - a/100) + s
//
// R1 showed 3x HBM write amplification (800 MB vs 268 MB ideal) from
// 16B-per-lane stores at 8KB lane stride (64 partial lines per store instr,
// evicted dirty before filling). Fix: stage 64x64 output tiles in LDS
// (stride 65, conflict-free), flush with coalesced full-line float4 stores.
// Inputs: full tile (16 float4) register-buffered, next tile prefetched at
// tile start -> ~4k cycles of latency cover. Single-wave blocks: no
// __syncthreads (would drain vmcnt and kill the prefetch); per-wave LDS
// ops are in-order so RAW/WAR on the tiles is safe.

#define LIF_L  2048
#define TILE   64
#define NTILES (LIF_L / TILE)   // 32
#define STRIDE 65               // 64 + 1 pad: bank = (lane + t) % 32, conflict-free

__device__ __forceinline__ float lif_step(float It, float& v, float& a, float& snum) {
    float th = __fadd_rn(1.0f, __fmul_rn(1.5f, a));
    float vn = __fadd_rn(__fsub_rn(v, __fdiv_rn(v, 20.0f)), It);
    bool fire = (vn >= th);
    float s = fire ? 1.0f : 0.0f;
    snum = __fadd_rn(snum, s);
    v = fire ? -0.5f : vn;
    a = __fadd_rn(__fsub_rn(a, __fdiv_rn(a, 100.0f)), s);
    return s;
}

__global__ __launch_bounds__(64, 1) void lif_fwd(const float* __restrict__ I,
                                                 float* __restrict__ spikes,
                                                 float* __restrict__ series) {
    __shared__ float sp_tile[64 * STRIDE];
    __shared__ float se_tile[64 * STRIDE];

    const int lane = threadIdx.x;        // one row per lane
    const int row0 = blockIdx.x * 64;
    const size_t rbase = (size_t)(row0 + lane) * LIF_L;
    const float4* __restrict__ I4 = reinterpret_cast<const float4*>(I + rbase);

    float v = 0.0f, a = 0.0f, snum = 0.0f;

    float4 cur[16], nxt[16];

    // Preload tile 0 into registers (strided per-lane loads; L1 holds the
    // 64 live lines per wave -> no read amplification, per R1 FETCH_SIZE).
    #pragma unroll
    for (int i = 0; i < 16; ++i) cur[i] = I4[i];

    for (int kt = 0; kt < NTILES; ++kt) {
        // Issue next tile's 16 loads now; 64 steps of compute hide them.
        if (kt + 1 < NTILES) {
            #pragma unroll
            for (int i = 0; i < 16; ++i) nxt[i] = I4[(kt + 1) * 16 + i];
        }

        // Compute 64 steps, results into LDS tiles (conflict-free writes).
        #pragma unroll
        for (int c = 0; c < 16; ++c) {
            float4 in = cur[c];
            float s0 = lif_step(in.x, v, a, snum); float n0 = snum;
            float s1 = lif_step(in.y, v, a, snum); float n1 = snum;
            float s2 = lif_step(in.z, v, a, snum); float n2 = snum;
            float s3 = lif_step(in.w, v, a, snum); float n3 = snum;
            int b = lane * STRIDE + c * 4;
            sp_tile[b + 0] = s0; sp_tile[b + 1] = s1;
            sp_tile[b + 2] = s2; sp_tile[b + 3] = s3;
            se_tile[b + 0] = n0; se_tile[b + 1] = n1;
            se_tile[b + 2] = n2; se_tile[b + 3] = n3;
        }

        // Coalesced flush: instruction i covers 4 rows x 256 B contiguous.
        const size_t colbase = (size_t)kt * TILE;
        #pragma unroll
        for (int i = 0; i < 16; ++i) {
            int idx = i * 64 + lane;
            int row = idx >> 4;          // 0..63
            int c4  = (idx & 15) * 4;    // 0,4,...,60
            int lb  = row * STRIDE + c4;
            float4 vs = make_float4(sp_tile[lb], sp_tile[lb + 1],
                                    sp_tile[lb + 2], sp_tile[lb + 3]);
            float4 ve = make_float4(se_tile[lb], se_tile[lb + 1],
                                    se_tile[lb + 2], se_tile[lb + 3]);
            size_t g = (size_t)(row0 + row) * LIF_L + colbase + c4;
            *reinterpret_cast<float4*>(spikes + g) = vs;
            *reinterpret_cast<float4*>(series + g) = ve;
        }

        // Rotate register tile.
        if (kt + 1 < NTILES) {
            #pragma unroll
            for (int i = 0; i < 16; ++i) cur[i] = nxt[i];
        }
    }
}

extern "C" void kernel_launch(void* const* d_in, const int* in_sizes, int n_in,
                              void* d_out, int out_size, void* d_ws, size_t ws_size,
                              hipStream_t stream) {
    const float* I = (const float*)d_in[0];
    const int B = in_sizes[0] / LIF_L;                  // 16384
    float* spikes = (float*)d_out;                      // (B, L)
    float* series = (float*)d_out + (size_t)B * LIF_L;  // (B, L)

    const int threads = 64;
    const int blocks = B / threads;                     // 256 blocks, 1 wave each
    lif_fwd<<<blocks, threads, 0, stream>>>(I, spikes, series);
}

// Round 3
// 410.610 us; speedup vs baseline: 1.4656x; 1.1669x over previous
//
#include <hip/hip_runtime.h>

// LIF forward recurrence, bit-exact vs the numpy fp32 reference.
//
// Per step (exact op order, correctly-rounded, no FMA contraction of the
// reference ops):
//   th   = 1 + 1.5*a
//   v    = (v - v/20) + I_t
//   s    = (v >= th) ? 1 : 0        // STE forward == s_hard exactly (Sterbenz)
//   snum += s
//   v    = s ? -0.5 : v             // exact for s in {0,1}
//   a    = (a - a/100) + s
//
// R1: fixed 3x HBM write amplification via LDS 64x64 tile transpose.
// R2 counters: 248 us, VALUBusy 11.6%, HBM 17% -> latency-bound on the
// serial chain; __fdiv_rn (~8 dependent instrs, ~65 cyc) x2 per step
// dominates. Fix: Markstein 3-op constant division, PROVABLY bit-exact:
//   q0 = rn(v*rh); r = fma(-d,q0,v); q = rn(q0 + r*rh)
// pre-rounding error <= 2^-47 rel, and v/d is never within ulp/10 of an
// f32 rounding midpoint for d=20,100 (d*midpoint needs a 5*odd / 25*odd
// mantissa > 24 bits -> impossible; integer gap >= ulp/10). So the final
// rn() lands identically to rn(v/d) for ALL v.

#define LIF_L  2048
#define TILE   64
#define NTILES (LIF_L / TILE)   // 32
#define STRIDE 65               // 64+1 pad: ds bank = (lane + t) % 32, conflict-free

__device__ __forceinline__ float div20(float v) {
    const float rh = 0.05f;                    // rn(1/20)
    float q0 = __fmul_rn(v, rh);
    float r  = __fmaf_rn(-20.0f, q0, v);       // exact-ish residual
    return __fmaf_rn(r, rh, q0);               // == __fdiv_rn(v, 20.0f) for all v
}

__device__ __forceinline__ float div100(float a) {
    const float rh = 0.01f;                    // rn(1/100)
    float q0 = __fmul_rn(a, rh);
    float r  = __fmaf_rn(-100.0f, q0, a);
    return __fmaf_rn(r, rh, q0);               // == __fdiv_rn(a, 100.0f) for all a
}

__device__ __forceinline__ float lif_step(float It, float& v, float& a, float& snum) {
    float th = __fadd_rn(1.0f, __fmul_rn(1.5f, a));
    float vn = __fadd_rn(__fsub_rn(v, div20(v)), It);
    bool fire = (vn >= th);
    float s = fire ? 1.0f : 0.0f;
    snum = __fadd_rn(snum, s);
    v = fire ? -0.5f : vn;
    a = __fadd_rn(__fsub_rn(a, div100(a)), s);
    return s;
}

__global__ __launch_bounds__(64, 1) void lif_fwd(const float* __restrict__ I,
                                                 float* __restrict__ spikes,
                                                 float* __restrict__ series) {
    __shared__ float sp_tile[64 * STRIDE];
    __shared__ float se_tile[64 * STRIDE];

    const int lane = threadIdx.x;        // one row (chain) per lane
    const int row0 = blockIdx.x * 64;
    const size_t rbase = (size_t)(row0 + lane) * LIF_L;
    const float4* __restrict__ I4 = reinterpret_cast<const float4*>(I + rbase);

    float v = 0.0f, a = 0.0f, snum = 0.0f;

    // Two full input tiles in registers (ping-pong): ~4k cycles of latency
    // cover per load batch, no rotate copies. Single-wave block: no
    // __syncthreads anywhere (per-wave LDS pipe is in-order).
    float4 bufA[16], bufB[16];

    #pragma unroll
    for (int i = 0; i < 16; ++i) bufA[i] = I4[i];
    #pragma unroll
    for (int i = 0; i < 16; ++i) bufB[i] = I4[16 + i];

    auto compute_tile = [&](float4* buf) {
        #pragma unroll
        for (int c = 0; c < 16; ++c) {
            float4 in = buf[c];
            float s0 = lif_step(in.x, v, a, snum); float n0 = snum;
            float s1 = lif_step(in.y, v, a, snum); float n1 = snum;
            float s2 = lif_step(in.z, v, a, snum); float n2 = snum;
            float s3 = lif_step(in.w, v, a, snum); float n3 = snum;
            int b = lane * STRIDE + c * 4;
            sp_tile[b + 0] = s0; sp_tile[b + 1] = s1;
            sp_tile[b + 2] = s2; sp_tile[b + 3] = s3;
            se_tile[b + 0] = n0; se_tile[b + 1] = n1;
            se_tile[b + 2] = n2; se_tile[b + 3] = n3;
        }
    };

    auto flush_tile = [&](int kt) {
        const size_t colbase = (size_t)kt * TILE;
        #pragma unroll
        for (int i = 0; i < 16; ++i) {
            int idx = i * 64 + lane;
            int row = idx >> 4;          // 0..63
            int c4  = (idx & 15) * 4;    // 0,4,...,60
            int lb  = row * STRIDE + c4;
            float4 vs = make_float4(sp_tile[lb], sp_tile[lb + 1],
                                    sp_tile[lb + 2], sp_tile[lb + 3]);
            float4 ve = make_float4(se_tile[lb], se_tile[lb + 1],
                                    se_tile[lb + 2], se_tile[lb + 3]);
            size_t g = (size_t)(row0 + row) * LIF_L + colbase + c4;
            *reinterpret_cast<float4*>(spikes + g) = vs;
            *reinterpret_cast<float4*>(series + g) = ve;
        }
    };

    for (int kt = 0; kt < NTILES; kt += 2) {
        compute_tile(bufA);
        if (kt + 2 < NTILES) {
            #pragma unroll
            for (int i = 0; i < 16; ++i) bufA[i] = I4[(kt + 2) * 16 + i];
        }
        flush_tile(kt);

        compute_tile(bufB);
        if (kt + 3 < NTILES) {
            #pragma unroll
            for (int i = 0; i < 16; ++i) bufB[i] = I4[(kt + 3) * 16 + i];
        }
        flush_tile(kt + 1);
    }
}

extern "C" void kernel_launch(void* const* d_in, const int* in_sizes, int n_in,
                              void* d_out, int out_size, void* d_ws, size_t ws_size,
                              hipStream_t stream) {
    const float* I = (const float*)d_in[0];
    const int B = in_sizes[0] / LIF_L;                  // 16384
    float* spikes = (float*)d_out;                      // (B, L)
    float* series = (float*)d_out + (size_t)B * LIF_L;  // (B, L)

    const int threads = 64;
    const int blocks = B / threads;                     // 256 blocks, 1 wave each
    lif_fwd<<<blocks, threads, 0, stream>>>(I, spikes, series);
}

// Round 4
// 390.416 us; speedup vs baseline: 1.5414x; 1.0517x over previous
//
#include <hip/hip_runtime.h>

// LIF forward recurrence, bit-exact vs the numpy fp32 reference.
//
// Per step (exact op order, correctly-rounded, never FMA-contracted):
//   th   = 1 + 1.5*a
//   v    = (v - v/20) + I_t
//   s    = (v >= th) ? 1 : 0        // STE forward == s_hard exactly (Sterbenz)
//   snum += s                       // s in {0,1} -> snum is exact integer <= 2048
//   v    = s ? -0.5 : v
//   a    = (a - a/100) + s
//
// R1: LDS 64x64 tile transpose killed 3x HBM write amplification.
// R2: Markstein 3-op constant division (provably == __fdiv_rn for d=20,100)
//     cut the serial chain ~3x.
// R4 (this): producer/consumer wave specialization. Wave 0 = pure
// recurrence, writes spike tiles to double-buffered LDS (no snum, no
// flush, no stores). Wave 1 (different SIMD) = per-row cumsum (exact:
// integer adds of {0,1} in reference order) + transposed coalesced
// flush of both outputs. One __syncthreads per 64-step tile; helper lags
// one tile so flush(k-1) overlaps compute(k).

#define LIF_L  2048
#define TILE   64
#define NTILES (LIF_L / TILE)   // 32
#define STRIDE 65               // pad: all LDS b128 patterns land 2 lanes/bank (free)

__device__ __forceinline__ float div20(float v) {
    const float rh = 0.05f;                    // rn(1/20)
    float q0 = __fmul_rn(v, rh);
    float r  = __fmaf_rn(-20.0f, q0, v);
    return __fmaf_rn(r, rh, q0);               // == __fdiv_rn(v, 20.0f) for all v
}

__device__ __forceinline__ float div100(float a) {
    const float rh = 0.01f;                    // rn(1/100)
    float q0 = __fmul_rn(a, rh);
    float r  = __fmaf_rn(-100.0f, q0, a);
    return __fmaf_rn(r, rh, q0);               // == __fdiv_rn(a, 100.0f) for all a
}

__device__ __forceinline__ float lif_step(float It, float& v, float& a) {
    float th = __fadd_rn(1.0f, __fmul_rn(1.5f, a));
    float vn = __fadd_rn(__fsub_rn(v, div20(v)), It);
    bool fire = (vn >= th);
    float s = fire ? 1.0f : 0.0f;
    v = fire ? -0.5f : vn;
    a = __fadd_rn(__fsub_rn(a, div100(a)), s);
    return s;
}

__global__ __launch_bounds__(128, 1) void lif_fwd(const float* __restrict__ I,
                                                  float* __restrict__ spikes,
                                                  float* __restrict__ series) {
    __shared__ float sp_tile[2][64 * STRIDE];  // double-buffered spike tiles
    __shared__ float se_tile[64 * STRIDE];     // helper-private series tile

    const int tid  = threadIdx.x;
    const int wave = tid >> 6;         // 0 = compute, 1 = helper
    const int lane = tid & 63;
    const int row0 = blockIdx.x * 64;

    // ---- compute-wave state ----
    const float4* __restrict__ I4 =
        reinterpret_cast<const float4*>(I + (size_t)(row0 + lane) * LIF_L);
    float v = 0.0f, a = 0.0f;
    float4 bufA[16], bufB[16];

    // ---- helper-wave state ----
    float carry = 0.0f;                // per-row running spike count (exact int)

    if (wave == 0) {
        #pragma unroll
        for (int i = 0; i < 16; ++i) bufA[i] = I4[i];
        #pragma unroll
        for (int i = 0; i < 16; ++i) bufB[i] = I4[16 + i];
    }

    auto compute_tile = [&](const float4* buf, float* sp) {
        #pragma unroll
        for (int c = 0; c < 16; ++c) {
            float4 in = buf[c];
            float s0 = lif_step(in.x, v, a);
            float s1 = lif_step(in.y, v, a);
            float s2 = lif_step(in.z, v, a);
            float s3 = lif_step(in.w, v, a);
            int b = lane * STRIDE + c * 4;    // bank (lane+4c)%32: 2 lanes/bank, free
            sp[b + 0] = s0; sp[b + 1] = s1;
            sp[b + 2] = s2; sp[b + 3] = s3;
        }
    };

    auto helper_tile = [&](int tkt, const float* sp) {
        // 1) per-row cumsum (lane = row): exact integer adds in reference order
        const int rb = lane * STRIDE;
        #pragma unroll
        for (int c = 0; c < 16; ++c) {
            float4 sv = make_float4(sp[rb + c*4], sp[rb + c*4 + 1],
                                    sp[rb + c*4 + 2], sp[rb + c*4 + 3]);
            float4 nv;
            carry = __fadd_rn(carry, sv.x); nv.x = carry;
            carry = __fadd_rn(carry, sv.y); nv.y = carry;
            carry = __fadd_rn(carry, sv.z); nv.z = carry;
            carry = __fadd_rn(carry, sv.w); nv.w = carry;
            se_tile[rb + c*4 + 0] = nv.x; se_tile[rb + c*4 + 1] = nv.y;
            se_tile[rb + c*4 + 2] = nv.z; se_tile[rb + c*4 + 3] = nv.w;
        }
        // 2) transposed coalesced flush: instr i covers 4 rows x 256 B
        const size_t colbase = (size_t)tkt * TILE;
        #pragma unroll
        for (int i = 0; i < 16; ++i) {
            int idx = i * 64 + lane;
            int row = idx >> 4;
            int c4  = (idx & 15) * 4;
            int lb  = row * STRIDE + c4;      // bank (h+4l+4i)%32: 2 lanes/bank, free
            float4 vs = make_float4(sp[lb], sp[lb + 1], sp[lb + 2], sp[lb + 3]);
            float4 ve = make_float4(se_tile[lb], se_tile[lb + 1],
                                    se_tile[lb + 2], se_tile[lb + 3]);
            size_t g = (size_t)(row0 + row) * LIF_L + colbase + c4;
            *reinterpret_cast<float4*>(spikes + g) = vs;
            *reinterpret_cast<float4*>(series + g) = ve;
        }
    };

    for (int kt = 0; kt < NTILES; kt += 2) {
        // tile kt (buffer 0)
        if (wave == 0) {
            compute_tile(bufA, sp_tile[0]);
            if (kt + 2 < NTILES) {
                #pragma unroll
                for (int i = 0; i < 16; ++i) bufA[i] = I4[(kt + 2) * 16 + i];
            }
        } else if (kt > 0) {
            helper_tile(kt - 1, sp_tile[1]);
        }
        __syncthreads();
        // tile kt+1 (buffer 1)
        if (wave == 0) {
            compute_tile(bufB, sp_tile[1]);
            if (kt + 3 < NTILES) {
                #pragma unroll
                for (int i = 0; i < 16; ++i) bufB[i] = I4[(kt + 3) * 16 + i];
            }
        } else {
            helper_tile(kt, sp_tile[0]);
        }
        __syncthreads();
    }
    // tail: last tile
    if (wave == 1) helper_tile(NTILES - 1, sp_tile[1]);
}

extern "C" void kernel_launch(void* const* d_in, const int* in_sizes, int n_in,
                              void* d_out, int out_size, void* d_ws, size_t ws_size,
                              hipStream_t stream) {
    const float* I = (const float*)d_in[0];
    const int B = in_sizes[0] / LIF_L;                  // 16384
    float* spikes = (float*)d_out;                      // (B, L)
    float* series = (float*)d_out + (size_t)B * LIF_L;  // (B, L)

    const int threads = 128;                            // 2 waves: compute + helper
    const int blocks = B / 64;                          // 256 blocks, 64 rows each
    lif_fwd<<<blocks, threads, 0, stream>>>(I, spikes, series);
}